// Round 1
// baseline (466.604 us; speedup 1.0000x reference)
//
#include <hip/hip_runtime.h>
#include <hip/hip_bf16.h>

// Problem constants
#define BATCH 4096
#define G     14271   // genes = GEMM K dim
#define H     24      // gene sets
#define KT    446     // ceil(G/32) k-tiles (446*32 = 14272, 1 pad)
#define MT1   892     // ceil(G/16) m-tiles for phase 1 (B matrix rows)
#define MTX   256     // 4096/16 m-tiles for x GEMMs
#define S1    4       // k-splits phase 1
#define SX    8       // k-splits x GEMMs
#define TPS1  112     // tiles per split phase 1 (last = 110)
#define TPSX  56      // tiles per split x GEMMs (last = 54)
#define GP    14272   // padded G rows for partial buffer

typedef __bf16 bf16x8 __attribute__((ext_vector_type(8)));
typedef float  f32x4  __attribute__((ext_vector_type(4)));

__device__ inline unsigned short bf16_bits(float f) {
    __bf16 h = (__bf16)f;
    return __builtin_bit_cast(unsigned short, h);
}
__device__ inline float bits_to_f32(unsigned short b) {
    return __builtin_bit_cast(float, (unsigned int)b << 16);
}

// ---------------- small kernels ----------------

// per-set gene counts n[h] via ballot+popc, int atomics (deterministic)
__global__ void k_counts(const float* __restrict__ w, int* __restrict__ counts) {
    int g = blockIdx.x * blockDim.x + threadIdx.x;
    bool valid = g < G;
    const float* row = w + (long)g * H;
#pragma unroll
    for (int h = 0; h < H; ++h) {
        bool bit = valid && (row[h] > 0.0f);
        unsigned long long ball = __ballot(bit);
        if ((threadIdx.x & 63) == 0) atomicAdd(&counts[h], (int)__popcll(ball));
    }
}

// consts: [0..23]=n  [24]=maxrank  [32..55]=uc_a  [56..79]=c2  [80..103]=inv_n
//         [104..127]=S (k_sumS)    [128..175]=mu  [176..223]=out_w*rsig (k3b)
__global__ void k_consts(const int* __restrict__ counts,
                         const float* __restrict__ maxrank_p,
                         float* __restrict__ consts) {
    __shared__ float smr;
    int t = threadIdx.x;
    if (t == 0) {
        int nm = 0;
        for (int h = 0; h < H; ++h) nm = max(nm, counts[h]);
        float mp = maxrank_p[0];
        if (mp < 0.0f) mp = 0.0f;
        smr = (float)nm + 10.0f + mp * 1000.0f;
        consts[24] = smr;
    }
    __syncthreads();
    if (t < H) {
        float n  = (float)counts[t];
        float mr = smr;
        float c1 = n * (n + 1.0f) * 0.5f;
        float c2 = 1.0f / (n * mr);
        consts[t]      = n;
        consts[32 + t] = 1.0f + c1 * c2;
        consts[56 + t] = c2;
        consts[80 + t] = 1.0f / n;
    }
}

// Fill MFMA B-fragment layouts with W01 (bf16 {0,1}).
// Frag layout: frag[(ktile*NT+nt)*64 + lane][j]  = Wc[k][col]
//   k   = ktile*32 + (lane>>4)*8 + j
//   col = nt*16 + (lane&15)
// W01f: NT=2 (cols 0..31, 24..31 zero).  C2f: NT=3, only cols<24 here (gs later).
__global__ void k_fillfrag(const float* __restrict__ w,
                           unsigned short* __restrict__ W01f,
                           unsigned short* __restrict__ C2f) {
    int id = blockIdx.x * blockDim.x + threadIdx.x;
    const int nW = KT * 2 * 64;
    const int nC = KT * 3 * 64;
    unsigned short* dst;
    int NT, tl;
    if (id < nW)       { dst = W01f; NT = 2; tl = id; }
    else               { tl = id - nW; if (tl >= nC) return; dst = C2f; NT = 3; }
    int lane  = tl & 63;
    int tile  = tl >> 6;          // = ktile*NT + nt
    int ktile = tile / NT;
    int nt    = tile % NT;
    int col   = nt * 16 + (lane & 15);
    int kbase = ktile * 32 + (lane >> 4) * 8;
    if (dst == C2f && col >= 24) return;  // gs region owned by k_reduce1
    unsigned short v[8];
#pragma unroll
    for (int j = 0; j < 8; ++j) {
        int k = kbase + j;
        v[j] = (k < G && col < H && (w[(long)k * H + col] > 0.0f))
                   ? (unsigned short)0x3F80 : (unsigned short)0;
    }
    unsigned short* p = dst + ((long)tile * 64 + lane) * 8;
#pragma unroll
    for (int j = 0; j < 8; ++j) p[j] = v[j];
}

// ---------------- GEMM core (no LDS, no barriers) ----------------
// One wave computes a 16-row x (NT*16)-col f32 partial over tiles [tile0,tile1).
// A is f32 row-major [M x G]; coefficients pre-swizzled bf16 frags.
template <int NT>
__device__ inline void gemm_wave(const float* __restrict__ A, int M, int mtile,
                                 const unsigned short* __restrict__ Wf,
                                 float mr, int tile0, int tile1,
                                 float* __restrict__ outp, int ldo, int lane) {
    int r = lane & 15, sub = lane >> 4;
    int row = mtile * 16 + r;
    long rowl = (row < M) ? row : (M - 1);
    const float* ap = A + rowl * (long)G;
    f32x4 acc[NT];
#pragma unroll
    for (int nt = 0; nt < NT; ++nt) acc[nt] = (f32x4){0.f, 0.f, 0.f, 0.f};
    int koff = sub * 8;
    int tfast = (tile1 < 445) ? tile1 : 445;
#pragma unroll 2
    for (int t = tile0; t < tfast; ++t) {
        const float* p = ap + t * 32 + koff;
        float a[8];
#pragma unroll
        for (int j = 0; j < 8; ++j) a[j] = p[j];
        bf16x8 af;
#pragma unroll
        for (int j = 0; j < 8; ++j) af[j] = (__bf16)fminf(a[j], mr);
        const unsigned short* fb = Wf + ((long)(t * NT) * 64 + lane) * 8;
#pragma unroll
        for (int nt = 0; nt < NT; ++nt) {
            bf16x8 bfr = *reinterpret_cast<const bf16x8*>(fb + (long)nt * 512);
            acc[nt] = __builtin_amdgcn_mfma_f32_16x16x32_bf16(af, bfr, acc[nt], 0, 0, 0);
        }
    }
    if (tile1 == KT) {  // guarded tail tile t=445 (k up to 14271, 1 pad col)
        const int t = 445;
        float a[8];
#pragma unroll
        for (int j = 0; j < 8; ++j) {
            int k = t * 32 + koff + j;
            a[j] = (k < G) ? ap[k] : 0.0f;
        }
        bf16x8 af;
#pragma unroll
        for (int j = 0; j < 8; ++j) af[j] = (__bf16)fminf(a[j], mr);
        const unsigned short* fb = Wf + ((long)(t * NT) * 64 + lane) * 8;
#pragma unroll
        for (int nt = 0; nt < NT; ++nt) {
            bf16x8 bfr = *reinterpret_cast<const bf16x8*>(fb + (long)nt * 512);
            acc[nt] = __builtin_amdgcn_mfma_f32_16x16x32_bf16(af, bfr, acc[nt], 0, 0, 0);
        }
    }
    // C/D layout: col = lane&15, row = (lane>>4)*4 + reg
    int ocol  = lane & 15;
    int orow0 = mtile * 16 + sub * 4;
#pragma unroll
    for (int nt = 0; nt < NT; ++nt)
#pragma unroll
        for (int rr = 0; rr < 4; ++rr) {
            int orow = orow0 + rr;
            if (orow < M) outp[(long)orow * ldo + nt * 16 + ocol] = acc[nt][rr];
        }
}

// merged launch: phase-1 (B @ W01, split 4) + rank GEMM (clamp, split 8)
__global__ __launch_bounds__(256) void k_gemm2(
    const float* __restrict__ Bmat, const float* __restrict__ xrank,
    const unsigned short* __restrict__ W01f, const float* __restrict__ consts,
    float* __restrict__ p1, float* __restrict__ rp) {
    int wid  = blockIdx.x * 4 + (threadIdx.x >> 6);
    int lane = threadIdx.x & 63;
    if (wid < MT1 * S1) {
        int mtile = wid >> 2, split = wid & 3;
        int tile0 = split * TPS1;
        int tile1 = (split == S1 - 1) ? KT : tile0 + TPS1;
        gemm_wave<2>(Bmat, G, mtile, W01f, 3.402823e38f, tile0, tile1,
                     p1 + (long)split * GP * 32, 32, lane);
    } else {
        int t = wid - MT1 * S1;
        int mtile = t >> 3, split = t & 7;
        int tile0 = split * TPSX;
        int tile1 = (split == SX - 1) ? KT : tile0 + TPSX;
        gemm_wave<2>(xrank, BATCH, mtile, W01f, consts[24], tile0, tile1,
                     rp + (long)split * BATCH * 32, 32, lane);
    }
}

__global__ __launch_bounds__(256) void k_gemm3(
    const float* __restrict__ xlog2, const unsigned short* __restrict__ C2f,
    float* __restrict__ lp) {
    int wid  = blockIdx.x * 4 + (threadIdx.x >> 6);
    int lane = threadIdx.x & 63;
    int mtile = wid >> 3, split = wid & 7;
    int tile0 = split * TPSX;
    int tile1 = (split == SX - 1) ? KT : tile0 + TPSX;
    gemm_wave<3>(xlog2, BATCH, mtile, C2f, 3.402823e38f, tile0, tile1,
                 lp + (long)split * BATCH * 48, 48, lane);
}

// reduce phase-1 k-split partials -> gs (bf16 into C2 frag cols 24..47) + block S partials
__global__ __launch_bounds__(256) void k_reduce1(const float* __restrict__ p1,
                                                 unsigned short* __restrict__ C2f,
                                                 float* __restrict__ blockS) {
    int k = blockIdx.x * 256 + threadIdx.x;  // enumerates frag k-slots 0..14271
    float gsr[H];
#pragma unroll
    for (int h = 0; h < H; ++h) gsr[h] = 0.0f;
    if (k < GP) {
        if (k < G) {
#pragma unroll
            for (int h = 0; h < H; ++h) {
                float s = 0.0f;
                for (int sp = 0; sp < S1; ++sp) s += p1[((long)sp * GP + k) * 32 + h];
                gsr[h] = s;
            }
        }
        int ktile = k >> 5, j = k & 7, lsub = (k >> 3) & 3;
#pragma unroll
        for (int h = 0; h < H; ++h) {
            unsigned short bits = bf16_bits(gsr[h]);
            int col = 24 + h, nt = col >> 4, lane = lsub * 16 + (col & 15);
            C2f[((long)(ktile * 3 + nt) * 64 + lane) * 8 + j] = bits;
            gsr[h] = bits_to_f32(bits);  // S from the rounded values (self-consistent)
        }
    }
    // deterministic reduction: wave shfl tree, then cross-wave via LDS
    __shared__ float sred[4][H];
    int lane = threadIdx.x & 63, w = threadIdx.x >> 6;
#pragma unroll
    for (int h = 0; h < H; ++h) {
        float v = gsr[h];
        for (int off = 1; off < 64; off <<= 1) v += __shfl_xor(v, off);
        if (lane == 0) sred[w][h] = v;
    }
    __syncthreads();
    if (threadIdx.x < H) {
        float s = sred[0][threadIdx.x] + sred[1][threadIdx.x] +
                  sred[2][threadIdx.x] + sred[3][threadIdx.x];
        blockS[blockIdx.x * H + threadIdx.x] = s;
    }
}

__global__ void k_sumS(const float* __restrict__ blockS, float* __restrict__ consts) {
    int t = threadIdx.x;
    if (t < H) {
        float s = 0.0f;
        for (int b = 0; b < 56; ++b) s += blockS[b * H + t];
        consts[104 + t] = s;
    }
}

// reduce x-GEMM partials, apply UCell/AMS transforms -> R_all [4096 x 48]
__global__ __launch_bounds__(256) void k3a(const float* __restrict__ rp,
                                           const float* __restrict__ lp,
                                           const float* __restrict__ consts,
                                           float* __restrict__ R_all) {
    int e = blockIdx.x * 256 + threadIdx.x;
    if (e >= BATCH * 48) return;
    int b = e / 48, c = e % 48;
    float v;
    if (c < 24) {
        float s = 0.0f;
        for (int sp = 0; sp < SX; ++sp) s += rp[((long)sp * BATCH + b) * 32 + c];
        v = consts[32 + c] - s * consts[56 + c];
    } else {
        int h = c - 24;
        float raw = 0.0f, bg = 0.0f;
        for (int sp = 0; sp < SX; ++sp) {
            const float* base = lp + ((long)sp * BATCH + b) * 48;
            raw += base[h];
            bg  += base[24 + h];
        }
        v = raw * consts[80 + h] - bg / consts[104 + h];
    }
    R_all[e] = v;
}

// per-column batch stats (f64), fold out_w into coef
__global__ __launch_bounds__(256) void k3b(const float* __restrict__ R_all,
                                           const float* __restrict__ out_w,
                                           float* __restrict__ consts) {
    int c = blockIdx.x;
    double s = 0.0, s2 = 0.0;
    for (int b = threadIdx.x; b < BATCH; b += 256) {
        double x = (double)R_all[(long)b * 48 + c];
        s += x; s2 += x * x;
    }
    __shared__ double sh1[256], sh2[256];
    sh1[threadIdx.x] = s; sh2[threadIdx.x] = s2;
    __syncthreads();
    for (int off = 128; off > 0; off >>= 1) {
        if (threadIdx.x < off) {
            sh1[threadIdx.x] += sh1[threadIdx.x + off];
            sh2[threadIdx.x] += sh2[threadIdx.x + off];
        }
        __syncthreads();
    }
    if (threadIdx.x == 0) {
        double mu  = sh1[0] / (double)BATCH;
        double var = sh2[0] / (double)BATCH - mu * mu;
        float rs = (float)(1.0 / sqrt(var + 1e-5));
        consts[128 + c] = (float)mu;
        consts[176 + c] = out_w[c] * rs;
    }
}

__global__ void k3c(const float* __restrict__ R_all, const float* __restrict__ consts,
                    const float* __restrict__ out_b, float* __restrict__ out) {
    int b = blockIdx.x * blockDim.x + threadIdx.x;
    if (b < BATCH) {
        float acc = out_b[0];
#pragma unroll
        for (int c = 0; c < 48; ++c)
            acc += consts[176 + c] * (R_all[(long)b * 48 + c] - consts[128 + c]);
        out[b] = acc;
    }
}

// ---------------- launch ----------------

extern "C" void kernel_launch(void* const* d_in, const int* in_sizes, int n_in,
                              void* d_out, int out_size, void* d_ws, size_t ws_size,
                              hipStream_t stream) {
    const float* x_rank    = (const float*)d_in[0];
    const float* x_log2    = (const float*)d_in[1];
    const float* Bmat      = (const float*)d_in[2];
    const float* weight    = (const float*)d_in[3];
    const float* maxrank_p = (const float*)d_in[4];
    const float* out_w     = (const float*)d_in[5];
    const float* out_b     = (const float*)d_in[6];

    char* ws = (char*)d_ws;
    size_t off = 0;
    auto alloc = [&](size_t bytes) {
        void* p = (void*)(ws + off);
        off = (off + bytes + 255) & ~(size_t)255;
        return p;
    };
    float*          consts = (float*)alloc(256 * 4);
    int*            counts = (int*)alloc(128);
    float*          blockS = (float*)alloc(56 * H * 4);
    unsigned short* W01f   = (unsigned short*)alloc((size_t)KT * 2 * 64 * 8 * 2);
    unsigned short* C2f    = (unsigned short*)alloc((size_t)KT * 3 * 64 * 8 * 2);
    float*          p1     = (float*)alloc((size_t)S1 * GP * 32 * 4);
    float*          rp     = (float*)alloc((size_t)SX * BATCH * 32 * 4);
    float*          lp     = (float*)alloc((size_t)SX * BATCH * 48 * 4);
    float*          R_all  = (float*)alloc((size_t)BATCH * 48 * 4);
    (void)ws_size; (void)in_sizes; (void)n_in; (void)out_size;

    hipMemsetAsync(counts, 0, 128, stream);
    k_counts  <<<56, 256, 0, stream>>>(weight, counts);
    k_consts  <<<1, 64, 0, stream>>>(counts, maxrank_p, consts);
    k_fillfrag<<<(KT * 2 * 64 + KT * 3 * 64 + 255) / 256, 256, 0, stream>>>(weight, W01f, C2f);
    k_gemm2   <<<(MT1 * S1 + MTX * SX) / 4, 256, 0, stream>>>(Bmat, x_rank, W01f, consts, p1, rp);
    k_reduce1 <<<56, 256, 0, stream>>>(p1, C2f, blockS);
    k_sumS    <<<1, 64, 0, stream>>>(blockS, consts);
    k_gemm3   <<<MTX * SX / 4, 256, 0, stream>>>(x_log2, C2f, lp);
    k3a       <<<BATCH * 48 / 256, 256, 0, stream>>>(rp, lp, consts, R_all);
    k3b       <<<48, 256, 0, stream>>>(R_all, out_w, consts);
    k3c       <<<16, 256, 0, stream>>>(R_all, consts, out_b, (float*)d_out);
}

// Round 2
// 381.452 us; speedup vs baseline: 1.2232x; 1.2232x over previous
//
#include <hip/hip_runtime.h>
#include <hip/hip_bf16.h>

// Problem constants
#define BATCH 4096
#define G     14271   // genes = GEMM K dim
#define H     24      // gene sets
#define KT    446     // ceil(G/32) k-tiles (446*32 = 14272, 1 pad)
#define NIT   223     // K iterations of BK=64 (2 k-tiles each)
#define MB1   223     // ceil(G/64) m-blocks for phase 1 (B matrix rows)
#define MBX   64      // 4096/64 m-blocks for x GEMMs
#define S1    8       // k-splits phase 1
#define SX    16      // k-splits x GEMMs
#define IPS1  28      // iters per split phase 1 (last = 27)
#define IPSX  14      // iters per split x GEMMs (last = 13)
#define GP    14272   // padded G rows for partial buffer
#define LDSTR 68      // LDS row stride in dwords (64 + 4 pad -> conflict-free b128)
#define FMAX  3.402823466e38f

typedef __bf16 bf16x8 __attribute__((ext_vector_type(8)));
typedef float  f32x4  __attribute__((ext_vector_type(4)));

__device__ inline unsigned short bf16_bits(float f) {
    __bf16 h = (__bf16)f;
    return __builtin_bit_cast(unsigned short, h);
}
__device__ inline float bits_to_f32(unsigned short b) {
    return __builtin_bit_cast(float, (unsigned int)b << 16);
}

// ---------------- small kernels ----------------

// per-set gene counts n[h] via ballot+popc, int atomics (deterministic)
__global__ void k_counts(const float* __restrict__ w, int* __restrict__ counts) {
    int g = blockIdx.x * blockDim.x + threadIdx.x;
    bool valid = g < G;
    const float* row = w + (long)g * H;
#pragma unroll
    for (int h = 0; h < H; ++h) {
        bool bit = valid && (row[h] > 0.0f);
        unsigned long long ball = __ballot(bit);
        if ((threadIdx.x & 63) == 0) atomicAdd(&counts[h], (int)__popcll(ball));
    }
}

// consts: [0..23]=n  [24]=maxrank  [32..55]=uc_a  [56..79]=c2  [80..103]=inv_n
//         [104..127]=S (k_sumS)    [128..175]=mu  [176..223]=out_w*rsig (k3b)
__global__ void k_consts(const int* __restrict__ counts,
                         const float* __restrict__ maxrank_p,
                         float* __restrict__ consts) {
    __shared__ float smr;
    int t = threadIdx.x;
    if (t == 0) {
        int nm = 0;
        for (int h = 0; h < H; ++h) nm = max(nm, counts[h]);
        float mp = maxrank_p[0];
        if (mp < 0.0f) mp = 0.0f;
        smr = (float)nm + 10.0f + mp * 1000.0f;
        consts[24] = smr;
    }
    __syncthreads();
    if (t < H) {
        float n  = (float)counts[t];
        float mr = smr;
        float c1 = n * (n + 1.0f) * 0.5f;
        float c2 = 1.0f / (n * mr);
        consts[t]      = n;
        consts[32 + t] = 1.0f + c1 * c2;
        consts[56 + t] = c2;
        consts[80 + t] = 1.0f / n;
    }
}

// Fill MFMA B-fragment layouts with W01 (bf16 {0,1}).
// Frag layout: frag[(ktile*NT+nt)*64 + lane][j]  = Wc[k][col]
//   k   = ktile*32 + (lane>>4)*8 + j
//   col = nt*16 + (lane&15)
// W01f: NT=2 (cols 0..31, 24..31 zero).  C2f: NT=3, only cols<24 here (gs later).
__global__ void k_fillfrag(const float* __restrict__ w,
                           unsigned short* __restrict__ W01f,
                           unsigned short* __restrict__ C2f) {
    int id = blockIdx.x * blockDim.x + threadIdx.x;
    const int nW = KT * 2 * 64;
    const int nC = KT * 3 * 64;
    unsigned short* dst;
    int NT, tl;
    if (id < nW)       { dst = W01f; NT = 2; tl = id; }
    else               { tl = id - nW; if (tl >= nC) return; dst = C2f; NT = 3; }
    int lane  = tl & 63;
    int tile  = tl >> 6;          // = ktile*NT + nt
    int ktile = tile / NT;
    int nt    = tile % NT;
    int col   = nt * 16 + (lane & 15);
    int kbase = ktile * 32 + (lane >> 4) * 8;
    if (dst == C2f && col >= 24) return;  // gs region owned by k_reduce1
    unsigned short v[8];
#pragma unroll
    for (int j = 0; j < 8; ++j) {
        int k = kbase + j;
        v[j] = (k < G && col < H && (w[(long)k * H + col] > 0.0f))
                   ? (unsigned short)0x3F80 : (unsigned short)0;
    }
    unsigned short* p = dst + ((long)tile * 64 + lane) * 8;
#pragma unroll
    for (int j = 0; j < 8; ++j) p[j] = v[j];
}

// ---------------- GEMM core: coalesced global_load_lds staging ----------------

// Stage 64 rows x 64 cols f32 tile into LDS (padded rows, LDSTR dwords).
// One global_load_lds per row: lane l writes buf[r*LDSTR + l] <- A[grow*G + k0 + l]
// (256B contiguous per instruction; tolerates 4B row alignment).
__device__ inline void stage_tile(const float* __restrict__ A, int M, int row0,
                                  int k0, bool clampk, float* buf,
                                  int wave, int lane) {
    int k = k0 + lane;
    if (clampk) k = (k < G) ? k : (G - 1);
#pragma unroll
    for (int i = 0; i < 16; ++i) {
        int r = wave * 16 + i;
        int grow = row0 + r;
        grow = (grow < M) ? grow : (M - 1);
        const float* src = A + (long)grow * G + k;
        __builtin_amdgcn_global_load_lds(
            (const __attribute__((address_space(1))) void*)src,
            (__attribute__((address_space(3))) void*)(buf + r * LDSTR),
            4, 0, 0);
    }
}

template <int NT>
__device__ inline void consume_tiles(const float* __restrict__ buf,
                                     const unsigned short* __restrict__ Wf,
                                     int ktile0, float mr, f32x4* acc,
                                     int wave, int lane) {
    int r = lane & 15, sub = lane >> 4;
    const float* rowp = buf + (wave * 16 + r) * LDSTR + sub * 8;
#pragma unroll
    for (int kt = 0; kt < 2; ++kt) {
        const float4* p = reinterpret_cast<const float4*>(rowp + kt * 32);
        float4 lo = p[0];
        float4 hi = p[1];
        float a[8] = {lo.x, lo.y, lo.z, lo.w, hi.x, hi.y, hi.z, hi.w};
        bf16x8 af;
#pragma unroll
        for (int j = 0; j < 8; ++j) af[j] = (__bf16)fminf(a[j], mr);
        const unsigned short* fb = Wf + ((long)((ktile0 + kt) * NT) * 64 + lane) * 8;
#pragma unroll
        for (int nt = 0; nt < NT; ++nt) {
            bf16x8 bfr = *reinterpret_cast<const bf16x8*>(fb + (long)nt * 512);
            acc[nt] = __builtin_amdgcn_mfma_f32_16x16x32_bf16(af, bfr, acc[nt], 0, 0, 0);
        }
    }
}

// One block: 64 rows x NT*16 cols partial over iters [it0,it1). 4 waves, each
// owns one 16-row subtile. Double-buffered LDS, stage(next) issued before
// consume(cur) so the syncthreads drain mostly overlaps compute.
template <int NT>
__device__ inline void gemm_block(const float* __restrict__ A, int M, int mblk,
                                  const unsigned short* __restrict__ Wf, float mr,
                                  int it0, int it1,
                                  float* __restrict__ outp, int ldo) {
    __shared__ __align__(16) float sbuf[2][64 * LDSTR];
    int wave = threadIdx.x >> 6, lane = threadIdx.x & 63;
    int row0 = mblk * 64;
    f32x4 acc[NT];
#pragma unroll
    for (int nt = 0; nt < NT; ++nt) acc[nt] = (f32x4){0.f, 0.f, 0.f, 0.f};

    stage_tile(A, M, row0, it0 * 64, it0 == NIT - 1, sbuf[0], wave, lane);
    __syncthreads();
    int cur = 0;
    for (int it = it0; it < it1; ++it) {
        if (it + 1 < it1)
            stage_tile(A, M, row0, (it + 1) * 64, (it + 1) == NIT - 1,
                       sbuf[cur ^ 1], wave, lane);
        consume_tiles<NT>(sbuf[cur], Wf, it * 2, mr, acc, wave, lane);
        __syncthreads();
        cur ^= 1;
    }
    // C/D layout: col = lane&15, row = (lane>>4)*4 + reg
    int ocol  = lane & 15;
    int sub   = lane >> 4;
    int orow0 = row0 + wave * 16 + sub * 4;
#pragma unroll
    for (int nt = 0; nt < NT; ++nt)
#pragma unroll
        for (int rr = 0; rr < 4; ++rr) {
            int orow = orow0 + rr;
            if (orow < M) outp[(long)orow * ldo + nt * 16 + ocol] = acc[nt][rr];
        }
}

// merged launch: phase-1 (B @ W01, split 8) + rank GEMM (clamp, split 16)
__global__ __launch_bounds__(256) void k_gemm2(
    const float* __restrict__ Bmat, const float* __restrict__ xrank,
    const unsigned short* __restrict__ W01f, const float* __restrict__ consts,
    float* __restrict__ p1, float* __restrict__ rp) {
    int bid = blockIdx.x;
    if (bid < MB1 * S1) {
        int mblk = bid >> 3, split = bid & 7;
        int it0 = split * IPS1;
        int it1 = min(it0 + IPS1, NIT);
        gemm_block<2>(Bmat, G, mblk, W01f, FMAX, it0, it1,
                      p1 + (long)split * GP * 32, 32);
    } else {
        int t = bid - MB1 * S1;
        int mblk = t >> 4, split = t & 15;
        int it0 = split * IPSX;
        int it1 = min(it0 + IPSX, NIT);
        gemm_block<2>(xrank, BATCH, mblk, W01f, consts[24], it0, it1,
                      rp + (long)split * BATCH * 32, 32);
    }
}

__global__ __launch_bounds__(256) void k_gemm3(
    const float* __restrict__ xlog2, const unsigned short* __restrict__ C2f,
    float* __restrict__ lp) {
    int bid = blockIdx.x;
    int mblk = bid >> 4, split = bid & 15;
    int it0 = split * IPSX;
    int it1 = min(it0 + IPSX, NIT);
    gemm_block<3>(xlog2, BATCH, mblk, C2f, FMAX, it0, it1,
                  lp + (long)split * BATCH * 48, 48);
}

// reduce phase-1 k-split partials -> gs (bf16 into C2 frag cols 24..47) + block S partials
__global__ __launch_bounds__(256) void k_reduce1(const float* __restrict__ p1,
                                                 unsigned short* __restrict__ C2f,
                                                 float* __restrict__ blockS) {
    int k = blockIdx.x * 256 + threadIdx.x;  // enumerates frag k-slots
    float gsr[H];
#pragma unroll
    for (int h = 0; h < H; ++h) gsr[h] = 0.0f;
    if (k < GP) {
        if (k < G) {
            for (int sp = 0; sp < S1; ++sp) {
                const float4* r4 = reinterpret_cast<const float4*>(
                    p1 + ((long)sp * GP + k) * 32);
#pragma unroll
                for (int q = 0; q < 6; ++q) {
                    float4 v = r4[q];
                    gsr[q * 4 + 0] += v.x;
                    gsr[q * 4 + 1] += v.y;
                    gsr[q * 4 + 2] += v.z;
                    gsr[q * 4 + 3] += v.w;
                }
            }
        }
        int ktile = k >> 5, j = k & 7, lsub = (k >> 3) & 3;
#pragma unroll
        for (int h = 0; h < H; ++h) {
            unsigned short bits = bf16_bits(gsr[h]);
            int col = 24 + h, nt = col >> 4, lane = lsub * 16 + (col & 15);
            C2f[((long)(ktile * 3 + nt) * 64 + lane) * 8 + j] = bits;
            gsr[h] = bits_to_f32(bits);  // S from the rounded values (self-consistent)
        }
    }
    // deterministic reduction: wave shfl tree, then cross-wave via LDS
    __shared__ float sred[4][H];
    int lane = threadIdx.x & 63, w = threadIdx.x >> 6;
#pragma unroll
    for (int h = 0; h < H; ++h) {
        float v = gsr[h];
        for (int off = 1; off < 64; off <<= 1) v += __shfl_xor(v, off);
        if (lane == 0) sred[w][h] = v;
    }
    __syncthreads();
    if (threadIdx.x < H) {
        float s = sred[0][threadIdx.x] + sred[1][threadIdx.x] +
                  sred[2][threadIdx.x] + sred[3][threadIdx.x];
        blockS[blockIdx.x * H + threadIdx.x] = s;
    }
}

__global__ void k_sumS(const float* __restrict__ blockS, float* __restrict__ consts) {
    int t = threadIdx.x;
    if (t < H) {
        float s = 0.0f;
        for (int b = 0; b < 56; ++b) s += blockS[b * H + t];
        consts[104 + t] = s;
    }
}

// reduce x-GEMM partials, apply UCell/AMS transforms -> R_all [4096 x 48]
__global__ __launch_bounds__(256) void k3a(const float* __restrict__ rp,
                                           const float* __restrict__ lp,
                                           const float* __restrict__ consts,
                                           float* __restrict__ R_all) {
    int e = blockIdx.x * 256 + threadIdx.x;
    if (e >= BATCH * 48) return;
    int b = e / 48, c = e % 48;
    float v;
    if (c < 24) {
        float s = 0.0f;
        for (int sp = 0; sp < SX; ++sp) s += rp[((long)sp * BATCH + b) * 32 + c];
        v = consts[32 + c] - s * consts[56 + c];
    } else {
        int h = c - 24;
        float raw = 0.0f, bg = 0.0f;
        for (int sp = 0; sp < SX; ++sp) {
            const float* base = lp + ((long)sp * BATCH + b) * 48;
            raw += base[h];
            bg  += base[24 + h];
        }
        v = raw * consts[80 + h] - bg / consts[104 + h];
    }
    R_all[e] = v;
}

// per-column batch stats (f64), fold out_w into coef
__global__ __launch_bounds__(256) void k3b(const float* __restrict__ R_all,
                                           const float* __restrict__ out_w,
                                           float* __restrict__ consts) {
    int c = blockIdx.x;
    double s = 0.0, s2 = 0.0;
    for (int b = threadIdx.x; b < BATCH; b += 256) {
        double x = (double)R_all[(long)b * 48 + c];
        s += x; s2 += x * x;
    }
    __shared__ double sh1[256], sh2[256];
    sh1[threadIdx.x] = s; sh2[threadIdx.x] = s2;
    __syncthreads();
    for (int off = 128; off > 0; off >>= 1) {
        if (threadIdx.x < off) {
            sh1[threadIdx.x] += sh1[threadIdx.x + off];
            sh2[threadIdx.x] += sh2[threadIdx.x + off];
        }
        __syncthreads();
    }
    if (threadIdx.x == 0) {
        double mu  = sh1[0] / (double)BATCH;
        double var = sh2[0] / (double)BATCH - mu * mu;
        float rs = (float)(1.0 / sqrt(var + 1e-5));
        consts[128 + c] = (float)mu;
        consts[176 + c] = out_w[c] * rs;
    }
}

__global__ void k3c(const float* __restrict__ R_all, const float* __restrict__ consts,
                    const float* __restrict__ out_b, float* __restrict__ out) {
    int b = blockIdx.x * blockDim.x + threadIdx.x;
    if (b < BATCH) {
        float acc = out_b[0];
#pragma unroll
        for (int c = 0; c < 48; ++c)
            acc += consts[176 + c] * (R_all[(long)b * 48 + c] - consts[128 + c]);
        out[b] = acc;
    }
}

// ---------------- launch ----------------

extern "C" void kernel_launch(void* const* d_in, const int* in_sizes, int n_in,
                              void* d_out, int out_size, void* d_ws, size_t ws_size,
                              hipStream_t stream) {
    const float* x_rank    = (const float*)d_in[0];
    const float* x_log2    = (const float*)d_in[1];
    const float* Bmat      = (const float*)d_in[2];
    const float* weight    = (const float*)d_in[3];
    const float* maxrank_p = (const float*)d_in[4];
    const float* out_w     = (const float*)d_in[5];
    const float* out_b     = (const float*)d_in[6];

    char* ws = (char*)d_ws;
    size_t off = 0;
    auto alloc = [&](size_t bytes) {
        void* p = (void*)(ws + off);
        off = (off + bytes + 255) & ~(size_t)255;
        return p;
    };
    float*          consts = (float*)alloc(256 * 4);
    int*            counts = (int*)alloc(128);
    float*          blockS = (float*)alloc(56 * H * 4);
    unsigned short* W01f   = (unsigned short*)alloc((size_t)KT * 2 * 64 * 8 * 2);
    unsigned short* C2f    = (unsigned short*)alloc((size_t)KT * 3 * 64 * 8 * 2);
    float*          p1     = (float*)alloc((size_t)S1 * GP * 32 * 4);
    float*          rp     = (float*)alloc((size_t)SX * BATCH * 32 * 4);
    float*          lp     = (float*)alloc((size_t)SX * BATCH * 48 * 4);
    float*          R_all  = (float*)alloc((size_t)BATCH * 48 * 4);
    (void)ws_size; (void)in_sizes; (void)n_in; (void)out_size;

    hipMemsetAsync(counts, 0, 128, stream);
    k_counts  <<<56, 256, 0, stream>>>(weight, counts);
    k_consts  <<<1, 64, 0, stream>>>(counts, maxrank_p, consts);
    k_fillfrag<<<(KT * 2 * 64 + KT * 3 * 64 + 255) / 256, 256, 0, stream>>>(weight, W01f, C2f);
    k_gemm2   <<<MB1 * S1 + MBX * SX, 256, 0, stream>>>(Bmat, x_rank, W01f, consts, p1, rp);
    k_reduce1 <<<56, 256, 0, stream>>>(p1, C2f, blockS);
    k_sumS    <<<1, 64, 0, stream>>>(blockS, consts);
    k_gemm3   <<<MBX * SX, 256, 0, stream>>>(x_log2, C2f, lp);
    k3a       <<<BATCH * 48 / 256, 256, 0, stream>>>(rp, lp, consts, R_all);
    k3b       <<<48, 256, 0, stream>>>(R_all, out_w, consts);
    k3c       <<<16, 256, 0, stream>>>(R_all, consts, out_b, (float*)d_out);
}